// Round 4
// baseline (573.994 us; speedup 1.0000x reference)
//
#include <hip/hip_runtime.h>
#include <hip/hip_bf16.h>
#include <stdint.h>

// ---------------- problem constants ----------------
constexpr int   SEQ  = 8192;
constexpr int   NB   = 64;
constexpr int   ND   = 16;
constexpr float DT    = 0.01f;
constexpr float BETA  = 0.25f;
constexpr float GAMMA = 0.5f;
constexpr float C1 = (0.5f - BETA) * DT * DT;
constexpr float C2 = (1.0f - GAMMA) * DT;
constexpr float C3 = BETA * DT * DT;
constexpr float C4 = GAMMA * DT;
constexpr float E1 = C1 + C3 + DT * C4;
constexpr float E2 = C2 + C4;
constexpr float GDT  = GAMMA * DT;
constexpr float BDT2 = BETA * DT * DT;

constexpr int LCH  = 16;     // chunk (scan granularity); chunk k owns steps [16k,16k+16), chunk0 [1,16)
constexpr int NCH  = 512;
constexpr size_t BSTRIDE = (size_t)SEQ * ND;
constexpr size_t UOFF = 0;
constexpr size_t VOFF = (size_t)NB * SEQ * ND;
constexpr size_t AOFF = 2 * VOFF;

// ws layout (float offsets), total ~4.5 MB
constexpr int WS_A1T  = 0;        // 256 (transposed)
constexpr int WS_A2T  = 256;
constexpr int WS_A3T  = 512;
constexpr int WS_G4   = 768;      // 1024 each, row-major 32x32
constexpr int WS_G16  = 1792;
constexpr int WS_G256 = 2816;
constexpr int WS_P1   = 3840;     // 2048  p1[row*64+b]
constexpr int WS_ADJ  = 5888;     // 2048  (G^15 - G^16) p1
constexpr int WS_GT   = 7936;     // 32*2048 group totals -> group starts
constexpr int WS_C    = 73472;    // 512*2048 chunk totals -> chunk starts

// =====================================================================
// K0: invert K_eff & M, A2/A3, G powers (G4,G16,G256), p1, ADJ, step-0 out.
// =====================================================================
__global__ __launch_bounds__(512) void setup_k(const float* __restrict__ F,
                                               const float* __restrict__ Mg,
                                               const float* __restrict__ Cg,
                                               const float* __restrict__ Kg,
                                               float* __restrict__ ws,
                                               float* __restrict__ out)
{
    __shared__ float sM[256], sC[256], sK[256];
    __shared__ float aug[16][33];
    __shared__ float A1s[256], A2s[256], A3s[256], Mis[256];
    __shared__ float bA[1024], bB[1024];
    __shared__ float sP1[2048], sQ[2048];
    const int tid = threadIdx.x;
    if (tid < 256) { sM[tid] = Mg[tid]; sC[tid] = Cg[tid]; sK[tid] = Kg[tid]; }
    __syncthreads();

    const int r = tid >> 5, c = tid & 31;
    // ---- invert K_eff = M + GDT*C + BDT2*K ----
    {
        float v;
        if (c < 16) v = sM[r*16+c] + GDT * sC[r*16+c] + BDT2 * sK[r*16+c];
        else        v = (c - 16 == r) ? 1.f : 0.f;
        aug[r][c] = v;
    }
    __syncthreads();
    for (int kk = 0; kk < 16; ++kk) {
        float pv   = aug[kk][kk];
        float fr   = aug[r][kk];
        float akc  = aug[kk][c];
        float curv = aug[r][c];
        __syncthreads();
        float inv = 1.0f / pv;
        aug[r][c] = (r == kk) ? curv * inv : fmaf(-fr * inv, akc, curv);
        __syncthreads();
    }
    if (tid < 256) A1s[tid] = aug[tid >> 4][(tid & 15) + 16];
    __syncthreads();

    // ---- invert M ----
    aug[r][c] = (c < 16) ? sM[r*16+c] : ((c - 16 == r) ? 1.f : 0.f);
    __syncthreads();
    for (int kk = 0; kk < 16; ++kk) {
        float pv   = aug[kk][kk];
        float fr   = aug[r][kk];
        float akc  = aug[kk][c];
        float curv = aug[r][c];
        __syncthreads();
        float inv = 1.0f / pv;
        aug[r][c] = (r == kk) ? curv * inv : fmaf(-fr * inv, akc, curv);
        __syncthreads();
    }
    if (tid < 256) Mis[tid] = aug[tid >> 4][(tid & 15) + 16];
    __syncthreads();

    // ---- A2 = A1*C , A3 = A1*K ----
    if (tid < 256) {
        const int rr = tid >> 4, cc = tid & 15;
        float a2 = 0.f, a3 = 0.f;
        #pragma unroll
        for (int j = 0; j < 16; ++j) {
            const float a = A1s[rr*16+j];
            a2 = fmaf(a, sC[j*16+cc], a2);
            a3 = fmaf(a, sK[j*16+cc], a3);
        }
        A2s[tid] = a2; A3s[tid] = a3;
    }
    __syncthreads();

    if (tid < 256) {
        const int j = tid >> 4, d = tid & 15;
        ws[WS_A1T + tid] = A1s[d*16+j];
        ws[WS_A2T + tid] = A2s[d*16+j];
        ws[WS_A3T + tid] = A3s[d*16+j];
    }

    // ---- a0 = Minv*F[:,0,:], p1 seed, step-0 outputs ----
    for (int t = tid; t < 1024; t += 512) {
        const int b = t >> 4, d = t & 15;
        float s0 = 0.f;
        #pragma unroll
        for (int j = 0; j < 16; ++j) s0 = fmaf(Mis[d*16+j], F[(size_t)b * BSTRIDE + j], s0);
        out[UOFF + (size_t)b * BSTRIDE + d] = 0.f;
        out[VOFF + (size_t)b * BSTRIDE + d] = 0.f;
        out[AOFF + (size_t)b * BSTRIDE + d] = s0;
        sP1[d*64 + b]        = C1 * s0;
        sP1[(16 + d)*64 + b] = C2 * s0;
        ws[WS_P1 + d*64 + b]        = C1 * s0;
        ws[WS_P1 + (16 + d)*64 + b] = C2 * s0;
    }

    // ---- build G ----
    for (int idx = tid; idx < 1024; idx += 512) {
        const int i = idx >> 5, j = idx & 31;
        float v;
        if (i < 16) {
            if (j < 16) v = ((i == j) ? 1.f : 0.f) - E1 * A3s[i*16+j];
            else        v = ((i == j - 16) ? DT : 0.f) - E1 * A2s[i*16+(j-16)];
        } else {
            const int i2 = i - 16;
            if (j < 16) v = -E2 * A3s[i2*16+j];
            else        v = ((i2 == j - 16) ? 1.f : 0.f) - E2 * A2s[i2*16+(j-16)];
        }
        bA[idx] = v;
    }
    __syncthreads();

    // ---- q = p1 - G*p1  (for ADJ = G^15 q = (G^15 - G^16) p1) ----
    const int qrow = tid >> 4, qb4 = (tid & 15) * 4;
    {
        float tmp[4];
        #pragma unroll
        for (int u = 0; u < 4; ++u) {
            float s = sP1[qrow*64 + qb4 + u];
            #pragma unroll
            for (int j = 0; j < 32; ++j) s = fmaf(-bA[qrow*32+j], sP1[j*64 + qb4 + u], s);
            tmp[u] = s;
        }
        __syncthreads();
        #pragma unroll
        for (int u = 0; u < 4; ++u) sQ[qrow*64 + qb4 + u] = tmp[u];
        __syncthreads();
    }
    // apply q <- Mx*q helper (inline, used with G, G^2, G^4, G^8)
    #define QMUL(MX) do {                                                    \
        float tmp[4];                                                        \
        _Pragma("unroll")                                                    \
        for (int u = 0; u < 4; ++u) {                                        \
            float s = 0.f;                                                   \
            _Pragma("unroll")                                                \
            for (int j = 0; j < 32; ++j) s = fmaf((MX)[qrow*32+j], sQ[j*64 + qb4 + u], s); \
            tmp[u] = s;                                                      \
        }                                                                    \
        __syncthreads();                                                     \
        _Pragma("unroll")                                                    \
        for (int u = 0; u < 4; ++u) sQ[qrow*64 + qb4 + u] = tmp[u];          \
        __syncthreads();                                                     \
    } while (0)

    QMUL(bA);   // q <- G q          (bit 0 of 15)

    // ---- 8 squarings: G^2..G^256; store G4,G16,G256; fold q bits 1..3 ----
    for (int s = 0; s < 8; ++s) {
        for (int idx = tid; idx < 1024; idx += 512) {
            const int i = idx >> 5, j = idx & 31;
            float acc = 0.f;
            #pragma unroll
            for (int q = 0; q < 32; ++q) acc = fmaf(bA[i*32+q], bA[q*32+j], acc);
            bB[idx] = acc;
        }
        __syncthreads();
        for (int idx = tid; idx < 1024; idx += 512) bA[idx] = bB[idx];
        __syncthreads();
        if (s == 1) for (int idx = tid; idx < 1024; idx += 512) ws[WS_G4   + idx] = bA[idx];
        if (s == 3) for (int idx = tid; idx < 1024; idx += 512) ws[WS_G16  + idx] = bA[idx];
        if (s == 7) for (int idx = tid; idx < 1024; idx += 512) ws[WS_G256 + idx] = bA[idx];
        if (s <= 2) { QMUL(bA); }    // s=0: G^2, s=1: G^4, s=2: G^8  -> total G^15
    }
    #undef QMUL
    for (int t = tid; t < 2048; t += 512) ws[WS_ADJ + t] = sQ[t];
}

// ---------------------------------------------------------------------
// Stage one 8-step half of chunk F into LDS (XOR-swizzled), aligned runs.
// sF[b*128 + (W ^ (b&31))], W = step_in_half*16 + d.
// ---------------------------------------------------------------------
__device__ __forceinline__ void stage_half(const float* __restrict__ F, float* __restrict__ sF,
                                           int l, int w, int sbase16, int h)
{
    const int lw = l & 31;
    const int W0 = 4*lw;
    #pragma unroll
    for (int p = 0; p < 8; ++p) {
        const int b = p*8 + w*2 + (l >> 5);
        const float4 x = *(const float4*)(F + (size_t)b * BSTRIDE + (size_t)(sbase16 + 8*h) * ND + W0);
        const int c = b & 31;
        sF[b*128 + ((W0+0) ^ c)] = x.x;
        sF[b*128 + ((W0+1) ^ c)] = x.y;
        sF[b*128 + ((W0+2) ^ c)] = x.z;
        sF[b*128 + ((W0+3) ^ c)] = x.w;
    }
}

// ---------------------------------------------------------------------
// One Newmark step, F from LDS (lane = batch), matrices via s_load.
// ---------------------------------------------------------------------
__device__ __forceinline__ void newmark_step_lds(uintptr_t wsa, const float* __restrict__ sF,
                                                 int l, int sin,
                                                 float up[16], float vp[16], float acc[16])
{
    uintptr_t wsl = wsa;
    asm volatile("" : "+s"(wsl));
    const float* __restrict__ A1t = (const float*)wsl;
    const float* __restrict__ A2t = A1t + 256;
    const float* __restrict__ A3t = A1t + 512;
    const int c = l & 31;
    float f[16];
    #pragma unroll
    for (int d = 0; d < 16; ++d) f[d] = sF[l*128 + ((sin*16 + d) ^ c)];
    #pragma unroll
    for (int d = 0; d < 16; ++d) acc[d] = 0.f;
    #pragma unroll
    for (int j = 0; j < 16; ++j) {
        const float fj = f[j], nu = -up[j], nv = -vp[j];
        #pragma unroll
        for (int d = 0; d < 16; ++d) {
            acc[d] = fmaf(A1t[j*16+d], fj, acc[d]);
            acc[d] = fmaf(A3t[j*16+d], nu, acc[d]);
            acc[d] = fmaf(A2t[j*16+d], nv, acc[d]);
        }
    }
    #pragma unroll
    for (int d = 0; d < 16; ++d) {
        up[d] = fmaf(DT, vp[d], up[d]);
        up[d] = fmaf(E1, acc[d], up[d]);
        vp[d] = fmaf(E2, acc[d], vp[d]);
    }
}

// ---------------------------------------------------------------------
// Newmark matvec with direct (per-lane) F read. acc only; no update.
// ---------------------------------------------------------------------
__device__ __forceinline__ void nm_core_direct(uintptr_t wsa, const float* __restrict__ F,
                                               int b, int s,
                                               const float up[16], const float vp[16], float acc[16])
{
    uintptr_t wsl = wsa;
    asm volatile("" : "+s"(wsl));
    const float* __restrict__ A1t = (const float*)wsl;
    const float* __restrict__ A2t = A1t + 256;
    const float* __restrict__ A3t = A1t + 512;
    const float4* fp = (const float4*)(F + (size_t)b * BSTRIDE + (size_t)s * ND);
    const float4 f0 = fp[0], f1 = fp[1], f2 = fp[2], f3 = fp[3];
    const float f[16] = {f0.x,f0.y,f0.z,f0.w, f1.x,f1.y,f1.z,f1.w,
                         f2.x,f2.y,f2.z,f2.w, f3.x,f3.y,f3.z,f3.w};
    #pragma unroll
    for (int d = 0; d < 16; ++d) acc[d] = 0.f;
    #pragma unroll
    for (int j = 0; j < 16; ++j) {
        const float fj = f[j], nu = -up[j], nv = -vp[j];
        #pragma unroll
        for (int d = 0; d < 16; ++d) {
            acc[d] = fmaf(A1t[j*16+d], fj, acc[d]);
            acc[d] = fmaf(A3t[j*16+d], nu, acc[d]);
            acc[d] = fmaf(A2t[j*16+d], nv, acc[d]);
        }
    }
}

__device__ __forceinline__ void nm_update(const float acc[16], float up[16], float vp[16])
{
    #pragma unroll
    for (int d = 0; d < 16; ++d) {
        up[d] = fmaf(DT, vp[d], up[d]);
        up[d] = fmaf(E1, acc[d], up[d]);
        vp[d] = fmaf(E2, acc[d], vp[d]);
    }
}

// =====================================================================
// K1: chunk totals (zero-seeded). 512 blocks x 256. Wave w = 4-step
// slice; G4 fold. Chunk 0 = steps [1,16) + ADJ correction.
// =====================================================================
__global__ __launch_bounds__(256, 2) void phase1_k(const float* __restrict__ F,
                                                   const float* ws_in,
                                                   float* __restrict__ cbuf)
{
    __shared__ float sF[64*128];   // 32 KB
    __shared__ float st[4][2048];  // 32 KB
    const int tid = threadIdx.x;
    const int l = tid & 63;
    const int w = tid >> 6;
    const int k = blockIdx.x;
    const int sbase16 = 16*k;
    const uintptr_t wsa = (uintptr_t)ws_in;

    float up[16], vp[16], acc[16];
    #pragma unroll
    for (int d = 0; d < 16; ++d) { up[d] = 0.f; vp[d] = 0.f; }

    const int sl_start = max(sbase16 + 4*w, 1);
    const int sl_n     = sbase16 + 4*w + 4 - sl_start;

    stage_half(F, sF, l, w, sbase16, 0);
    __syncthreads();
    if (w < 2) {
        for (int i = 0; i < sl_n; ++i)
            newmark_step_lds(wsa, sF, l, sl_start - sbase16 + i, up, vp, acc);
        #pragma unroll
        for (int d = 0; d < 16; ++d) { st[w][d*64 + l] = up[d]; st[w][(16+d)*64 + l] = vp[d]; }
    }
    __syncthreads();
    stage_half(F, sF, l, w, sbase16, 1);
    __syncthreads();
    if (w >= 2) {
        for (int i = 0; i < sl_n; ++i)
            newmark_step_lds(wsa, sF, l, sl_start - sbase16 - 8 + i, up, vp, acc);
        #pragma unroll
        for (int d = 0; d < 16; ++d) { st[w][d*64 + l] = up[d]; st[w][(16+d)*64 + l] = vp[d]; }
    }
    __syncthreads();

    // fold: st[r] <- G4*st[r-1] + st[r]
    const int wr = __builtin_amdgcn_readfirstlane(tid >> 6);
    const uintptr_t g4a = (uintptr_t)(ws_in + WS_G4);
    float n[8];
    for (int rr = 1; rr < 4; ++rr) {
        uintptr_t gl = g4a; asm volatile("" : "+s"(gl));
        const float* __restrict__ G4 = (const float*)gl;
        #pragma unroll
        for (int q = 0; q < 8; ++q) n[q] = st[rr][(wr+4*q)*64 + l];
        #pragma unroll
        for (int j = 0; j < 32; ++j) {
            const float pj = st[rr-1][j*64 + l];
            #pragma unroll
            for (int q = 0; q < 8; ++q) n[q] = fmaf(G4[(wr+4*q)*32 + j], pj, n[q]);
        }
        if (rr < 3) {
            #pragma unroll
            for (int q = 0; q < 8; ++q) st[rr][(wr+4*q)*64 + l] = n[q];
            __syncthreads();
        }
    }
    if (k == 0) {
        #pragma unroll
        for (int q = 0; q < 8; ++q) n[q] += ws_in[WS_ADJ + (wr+4*q)*64 + l];
    }
    #pragma unroll
    for (int q = 0; q < 8; ++q) cbuf[(size_t)k * 2048 + (wr+4*q)*64 + l] = n[q];
}

// =====================================================================
// K2: affine scan  p' = Gm*p + c_k, pipelined c prefetch.
// =====================================================================
__global__ __launch_bounds__(256) void scan_k(const float* Gm_in,
                                              float* __restrict__ cbase,
                                              const float* __restrict__ seed,
                                              float* __restrict__ totals,
                                              int nIter)
{
    __shared__ float pb[2][2048];
    const int tid = threadIdx.x;
    const int b = tid & 63;
    const int w = __builtin_amdgcn_readfirstlane((int)(tid >> 6));
    const int g = blockIdx.x;
    const uintptr_t ga = (uintptr_t)Gm_in;
    float pr[8];
    #pragma unroll
    for (int q = 0; q < 8; ++q) {
        const int rrow = w + 4*q;
        pr[q] = seed ? seed[(size_t)g * 2048 + rrow*64 + b] : 0.f;
        pb[0][rrow*64 + b] = pr[q];
    }
    __syncthreads();
    int cur = 0;
    float* cslot = cbase + (size_t)g * nIter * 2048;
    float nq[8];
    #pragma unroll
    for (int q = 0; q < 8; ++q) nq[q] = cslot[(w + 4*q)*64 + b];
    for (int k = 0; k < nIter; ++k) {
        float nn[8];
        if (k + 1 < nIter) {
            #pragma unroll
            for (int q = 0; q < 8; ++q) nn[q] = cslot[2048 + (w + 4*q)*64 + b];
        }
        if (!totals) {
            #pragma unroll
            for (int q = 0; q < 8; ++q) cslot[(w + 4*q)*64 + b] = pr[q];
        }
        uintptr_t gl = ga; asm volatile("" : "+s"(gl));
        const float* __restrict__ Gm = (const float*)gl;
        float n[8];
        #pragma unroll
        for (int q = 0; q < 8; ++q) n[q] = nq[q];
        const float* prow = pb[cur];
        #pragma unroll
        for (int j = 0; j < 32; ++j) {
            const float pj = prow[j*64 + b];
            #pragma unroll
            for (int q = 0; q < 8; ++q) n[q] = fmaf(Gm[(w + 4*q)*32 + j], pj, n[q]);
        }
        #pragma unroll
        for (int q = 0; q < 8; ++q) { pr[q] = n[q]; pb[cur ^ 1][(w + 4*q)*64 + b] = n[q]; nq[q] = nn[q]; }
        cur ^= 1;
        cslot += 2048;
        __syncthreads();
    }
    if (totals) {
        #pragma unroll
        for (int q = 0; q < 8; ++q) totals[(size_t)g * 2048 + (w + 4*q)*64 + b] = pr[q];
    }
}

// ---------------------------------------------------------------------
// Drain one array's out-slice from a wave's LDS quadrant to global.
// souq[b*64 + (e ^ (b&31))], e = i*16+d. Run = out_n*64 B, 256B-aligned
// for k>=1 (out_s0 % 4 == 0). 2-way LDS banking (free).
// ---------------------------------------------------------------------
__device__ __forceinline__ void drain_quad(const float* __restrict__ souq,
                                           float* __restrict__ garr,
                                           int l, int out_s0, int out_n)
{
    const int m = l & 15, dlt = l >> 4;
    const bool ok = (4*m) < out_n*16;
    #pragma unroll
    for (int g = 0; g < 16; ++g) {
        const int bq = g*4 + dlt;
        const int cb = bq & 31;
        float4 x;
        x.x = souq[bq*64 + ((4*m+0) ^ cb)];
        x.y = souq[bq*64 + ((4*m+1) ^ cb)];
        x.z = souq[bq*64 + ((4*m+2) ^ cb)];
        x.w = souq[bq*64 + ((4*m+3) ^ cb)];
        if (ok) *(float4*)(garr + (size_t)bq * BSTRIDE + (size_t)out_s0 * ND + 4*m) = x;
    }
}

// =====================================================================
// K3: outputs. 512 blocks x 256. NO barriers: wave w owns a private
// 16 KB LDS quadrant; warm-up ladder (direct per-lane F reads, L3-hot),
// then 4 output steps staged + drained as aligned 256 B runs per array.
// =====================================================================
__global__ __launch_bounds__(256, 2) void phase3_k(const float* __restrict__ F,
                                                   const float* ws_in,
                                                   const float* __restrict__ starts,
                                                   float* __restrict__ out)
{
    __shared__ float so[4][4096];   // 64 KB, one 16 KB quadrant per wave
    const int tid = threadIdx.x;
    const int b = tid & 63;
    const int w = tid >> 6;
    const int k = blockIdx.x;
    const uintptr_t wsa = (uintptr_t)ws_in;

    float up[16], vp[16], acc[16];
    const float* stt = starts + (size_t)k * 2048;
    #pragma unroll
    for (int d = 0; d < 16; ++d) { up[d] = stt[d*64 + b]; vp[d] = stt[(16+d)*64 + b]; }

    const int sbase  = (k == 0) ? 1 : 16*k;
    const int t0     = 16*k + 4*w;
    const int warm_n = (t0 > sbase) ? (t0 - sbase) : 0;
    const int out_s0 = (t0 > 1) ? t0 : 1;
    const int out_n  = t0 + 4 - out_s0;

    for (int i = 0; i < warm_n; ++i) {
        nm_core_direct(wsa, F, b, sbase + i, up, vp, acc);
        nm_update(acc, up, vp);
    }

    float vo[4][16], ao[4][16];
    float* souq = &so[w][0];
    const int cb0 = b & 31;
    for (int i = 0; i < out_n; ++i) {
        nm_core_direct(wsa, F, b, out_s0 + i, up, vp, acc);
        #pragma unroll
        for (int d = 0; d < 16; ++d) {
            souq[b*64 + ((i*16+d) ^ cb0)] = fmaf(C3, acc[d], up[d]);
            vo[i][d] = fmaf(C4, acc[d], vp[d]);
            ao[i][d] = acc[d];
        }
        nm_update(acc, up, vp);
    }
    drain_quad(souq, out + UOFF, b, out_s0, out_n);
    for (int i = 0; i < out_n; ++i) {
        #pragma unroll
        for (int d = 0; d < 16; ++d) souq[b*64 + ((i*16+d) ^ cb0)] = vo[i][d];
    }
    drain_quad(souq, out + VOFF, b, out_s0, out_n);
    for (int i = 0; i < out_n; ++i) {
        #pragma unroll
        for (int d = 0; d < 16; ++d) souq[b*64 + ((i*16+d) ^ cb0)] = ao[i][d];
    }
    drain_quad(souq, out + AOFF, b, out_s0, out_n);
}

// =====================================================================
extern "C" void kernel_launch(void* const* d_in, const int* in_sizes, int n_in,
                              void* d_out, int out_size, void* d_ws, size_t ws_size,
                              hipStream_t stream)
{
    const float* F = (const float*)d_in[0];
    const float* M = (const float*)d_in[1];
    const float* C = (const float*)d_in[2];
    const float* K = (const float*)d_in[3];
    float* out = (float*)d_out;
    float* ws  = (float*)d_ws;

    setup_k <<<1,   512, 0, stream>>>(F, M, C, K, ws, out);
    phase1_k<<<NCH, 256, 0, stream>>>(F, ws, ws + WS_C);
    // 512 chunks = 32 groups x 16
    scan_k  <<<32,  256, 0, stream>>>(ws + WS_G16,  ws + WS_C,  nullptr,     ws + WS_GT, 16);
    scan_k  <<<1,   256, 0, stream>>>(ws + WS_G256, ws + WS_GT, ws + WS_P1,  nullptr,    32);
    scan_k  <<<32,  256, 0, stream>>>(ws + WS_G16,  ws + WS_C,  ws + WS_GT,  nullptr,    16);
    phase3_k<<<NCH, 256, 0, stream>>>(F, ws, ws + WS_C, out);
}